// Round 3
// baseline (230.657 us; speedup 1.0000x reference)
//
#include <hip/hip_runtime.h>
#include <stdint.h>

// Problem: B=4, N=8192, F=64, L=2
//   z = x; repeat 2x: z = relu( A @ z @ W_l )   per batch
// Restructure: relu((A z) W) == relu(A (z W))  -> per layer:
//   1) zw kernel:  Zt[c=b*64+g][n] = sum_f z[b,n,f] * W_l[f,g]   (bf16, K-major)
//   2) gemm8: P[s][m][c] = sum_{k in chunk s} A[m,k] * Zt[c][k]   (bf16 MFMA, fp32 acc)
//      BM=256 BN=256(=N) BK=32, triple-buffered LDS, counted vmcnt(4) (never 0),
//      2 MFMA-phases/tile + setprio, 8 waves (2x4, wave tile 128x64), splitK=8,
//      grid 256 = 1 block/CU, s=bid%8 -> per-XCD Zt panel in L2.
//      BK=32 frag reads are a bijection onto contiguous 1KB chunks -> conflict-free,
//      no swizzle needed (staging is natural linear).
//   3) combine: z_next[m][c] = relu(sum_s P[s][m][c])
// A converted once f32->bf16 (128 MiB, L3-resident for the layer-2 read).
//
// ws: [0,128Mi) A_bf16 | [128Mi,+4Mi) Zt | [+4Mi) z1 | [136Mi,+64Mi) P

#define MK 8192

typedef float f32x4 __attribute__((ext_vector_type(4)));
typedef uint32_t u32x4 __attribute__((ext_vector_type(4)));
typedef uint32_t u32x2 __attribute__((ext_vector_type(2)));
typedef __bf16 bf16x8 __attribute__((ext_vector_type(8)));

__device__ inline uint16_t f2bf(float f) {
  uint32_t u = __builtin_bit_cast(uint32_t, f);
  u += 0x7fffu + ((u >> 16) & 1u);   // round-to-nearest-even (inputs are finite randn)
  return (uint16_t)(u >> 16);
}

// ---------------- A f32 -> bf16 (256 MB read, 128 MB write, pure streaming) ---------------
__global__ __launch_bounds__(256) void cvtA(const float* __restrict__ A, uint16_t* __restrict__ Ab) {
  const uint64_t total = (uint64_t)MK * MK;
  uint64_t i = ((uint64_t)blockIdx.x * 256 + threadIdx.x) * 8;
  const uint64_t stride = (uint64_t)gridDim.x * 256 * 8;
  for (; i < total; i += stride) {
    f32x4 v0 = *(const f32x4*)(A + i);
    f32x4 v1 = *(const f32x4*)(A + i + 4);
    u32x4 w;
    w[0] = (uint32_t)f2bf(v0[0]) | ((uint32_t)f2bf(v0[1]) << 16);
    w[1] = (uint32_t)f2bf(v0[2]) | ((uint32_t)f2bf(v0[3]) << 16);
    w[2] = (uint32_t)f2bf(v1[0]) | ((uint32_t)f2bf(v1[1]) << 16);
    w[3] = (uint32_t)f2bf(v1[2]) | ((uint32_t)f2bf(v1[3]) << 16);
    *(u32x4*)(Ab + i) = w;
  }
}

// ---------------- Zt = (z @ W_l)^T, stored [256][8192] bf16 -------------------------------
template <int LAYER>
__global__ __launch_bounds__(256) void zw_kernel(const float* __restrict__ x,
                                                 const uint16_t* __restrict__ z1,
                                                 const float* __restrict__ net,
                                                 uint16_t* __restrict__ Zt) {
  __shared__ float Wl[64 * 64];
  __shared__ float rows[64][65];
  const int b = blockIdx.y;
  const int n0 = blockIdx.x * 64;
  const int tid = threadIdx.x;

  const float* Wsrc = net + LAYER * 4096;
  for (int i = tid * 4; i < 4096; i += 1024) {
    f32x4 v = *(const f32x4*)(Wsrc + i);
    Wl[i] = v[0]; Wl[i + 1] = v[1]; Wl[i + 2] = v[2]; Wl[i + 3] = v[3];
  }
  if (LAYER == 0) {
    const float* src = x + ((uint64_t)b * MK + n0) * 64;
    for (int i = tid * 4; i < 4096; i += 1024) {
      f32x4 v = *(const f32x4*)(src + i);
      int r = i >> 6, f = i & 63;
      rows[r][f] = v[0]; rows[r][f + 1] = v[1]; rows[r][f + 2] = v[2]; rows[r][f + 3] = v[3];
    }
  } else {
    for (int i = tid * 8; i < 4096; i += 2048) {
      int r = i >> 6, f = i & 63;
      u32x4 v = *(const u32x4*)(z1 + (uint64_t)(n0 + r) * 256 + b * 64 + f);
#pragma unroll
      for (int j = 0; j < 4; ++j) {
        rows[r][f + 2 * j]     = __builtin_bit_cast(float, (v[j] & 0xffffu) << 16);
        rows[r][f + 2 * j + 1] = __builtin_bit_cast(float, v[j] & 0xffff0000u);
      }
    }
  }
  __syncthreads();

  const int nl = tid & 63;
  const int g0 = (tid >> 6) * 16;
  float s[16];
#pragma unroll
  for (int j = 0; j < 16; ++j) s[j] = 0.f;
  for (int f = 0; f < 64; ++f) {
    float rv = rows[nl][f];
#pragma unroll
    for (int j = 0; j < 16; ++j) s[j] = fmaf(rv, Wl[f * 64 + g0 + j], s[j]);
  }
  uint16_t* dst = Zt + (uint64_t)(b * 64 + g0) * MK + n0 + nl;
#pragma unroll
  for (int j = 0; j < 16; ++j) dst[(uint64_t)j * MK] = f2bf(s[j]);
}

// ---------------- pipelined split-K GEMM --------------------------------------------------
#define GLD(src, dstbase)                                                                   \
  __builtin_amdgcn_global_load_lds((const __attribute__((address_space(1))) uint32_t*)(src), \
                                   (__attribute__((address_space(3))) uint32_t*)(dstbase),   \
                                   16, 0, 0)

__global__ __launch_bounds__(512, 2) void gemm8(const uint16_t* __restrict__ Ab,
                                                const uint16_t* __restrict__ Bt,
                                                float* __restrict__ P) {
  __shared__ __align__(16) uint16_t As[3][8192];   // 3 bufs x (256 rows x 32 k) = 48 KB
  __shared__ __align__(16) uint16_t Bs[3][8192];   // 48 KB
  const int bid = (int)blockIdx.x;
  const int s = bid & 7, bm = bid >> 3;            // s=bid%8: one K-chunk per XCD
  const int row0 = bm * 256;
  const int k0 = s * 1024;                         // K-chunk of 1024 = 32 BK-tiles
  const int tid = threadIdx.x, wid = tid >> 6, lane = tid & 63;
  const int wr = wid >> 2, wc = wid & 3;           // 2x4 waves, wave tile 128x64

  // staging geometry: chunk = 16 rows x 32 k = 1 KB, lane l -> row +(l>>2), k +(l&3)*8.
  // wave w stages A chunks {2w,2w+1} and B chunks {2w,2w+1}; 4 gloads/thread/tile.
  const int srow = lane >> 2, sq = (lane & 3) * 8;
  const uint16_t* gA0 = Ab + (uint64_t)(row0 + (2 * wid) * 16 + srow) * MK + k0 + sq;
  const uint16_t* gA1 = gA0 + 16 * MK;
  const uint16_t* gB0 = Bt + (uint64_t)((2 * wid) * 16 + srow) * MK + k0 + sq;
  const uint16_t* gB1 = gB0 + 16 * MK;
  const int lcA0 = (2 * wid) * 512, lcA1 = lcA0 + 512;   // wave-uniform LDS chunk bases

  // fragment read bases (bijective onto 1KB chunks -> conflict-free, no swizzle)
  const int aBase = (wr * 128 + (lane & 15)) * 32 + (lane >> 4) * 8;
  const int bBase = (wc * 64 + (lane & 15)) * 32 + (lane >> 4) * 8;

  f32x4 acc[8][4] = {};

  // prologue: stage tiles 0,1 into bufs 0,1
#pragma unroll
  for (int t = 0; t < 2; ++t) {
    GLD(gA0 + t * 32, &As[t][lcA0]);
    GLD(gA1 + t * 32, &As[t][lcA1]);
    GLD(gB0 + t * 32, &Bs[t][lcA0]);
    GLD(gB1 + t * 32, &Bs[t][lcA1]);
  }
  asm volatile("s_waitcnt vmcnt(4)" ::: "memory");   // tile-0's 4 landed; tile-1's in flight
  __builtin_amdgcn_s_barrier();

  int buf = 0;
  for (int t = 0; t < 32; ++t) {
    const int nbuf = (buf >= 1) ? buf - 1 : 2;       // (t+2)%3: never a live buffer
    const int tko = ((t + 2 < 32) ? t + 2 : 31) * 32;  // clamp keeps vmcnt ledger uniform

    // ---- phase 0: reads (A m0-3, B all) | prefetch issue | barrier | 16 MFMA ----
    bf16x8 a0[4], b0[4];
#pragma unroll
    for (int mi = 0; mi < 4; ++mi) a0[mi] = *(const bf16x8*)&As[buf][aBase + mi * 512];
#pragma unroll
    for (int n = 0; n < 4; ++n) b0[n] = *(const bf16x8*)&Bs[buf][bBase + n * 512];
    GLD(gA0 + tko, &As[nbuf][lcA0]);
    GLD(gB0 + tko, &Bs[nbuf][lcA0]);
    __builtin_amdgcn_s_barrier();
    __builtin_amdgcn_s_setprio(1);
#pragma unroll
    for (int mi = 0; mi < 4; ++mi)
#pragma unroll
      for (int n = 0; n < 4; ++n)
        acc[mi][n] = __builtin_amdgcn_mfma_f32_16x16x32_bf16(a0[mi], b0[n], acc[mi][n], 0, 0, 0);
    __builtin_amdgcn_s_setprio(0);
    __builtin_amdgcn_s_barrier();

    // ---- phase 1: reads (A m4-7) | prefetch issue | barrier | 16 MFMA ----
    bf16x8 a1[4];
#pragma unroll
    for (int mi = 0; mi < 4; ++mi) a1[mi] = *(const bf16x8*)&As[buf][aBase + (mi + 4) * 512];
    GLD(gA1 + tko, &As[nbuf][lcA1]);
    GLD(gB1 + tko, &Bs[nbuf][lcA1]);
    __builtin_amdgcn_s_barrier();
    __builtin_amdgcn_s_setprio(1);
#pragma unroll
    for (int mi = 0; mi < 4; ++mi)
#pragma unroll
      for (int n = 0; n < 4; ++n)
        acc[mi + 4][n] = __builtin_amdgcn_mfma_f32_16x16x32_bf16(a1[mi], b0[n], acc[mi + 4][n], 0, 0, 0);
    __builtin_amdgcn_s_setprio(0);
    // counted wait: own tile-(t+1) loads (older than this tile's 4 issues) are done;
    // barrier makes that true for every thread's loads -> next tile's reads are safe.
    asm volatile("s_waitcnt vmcnt(4)" ::: "memory");
    __builtin_amdgcn_s_barrier();
    buf = (buf == 2) ? 0 : buf + 1;
  }

  float* Pp = P + (uint64_t)s * 2097152;
  const int lr = (lane >> 4) * 4, lc = lane & 15;
#pragma unroll
  for (int mi = 0; mi < 8; ++mi)
#pragma unroll
    for (int n = 0; n < 4; ++n) {
      const int gr = row0 + wr * 128 + mi * 16 + lr;
      const int gc = wc * 64 + n * 16 + lc;
#pragma unroll
      for (int j = 0; j < 4; ++j)
        Pp[(uint64_t)(gr + j) * 256 + gc] = acc[mi][n][j];
    }
}

// ---------------- combine: z = relu(sum_s P[s]); write bf16 z1 or final f32 out -----------
template <int OUT_MODE>  // 0: z1 bf16 [8192][256]; 1: out f32 [4][8192][64]
__global__ __launch_bounds__(256) void combine(const float* __restrict__ P,
                                               uint16_t* __restrict__ z1,
                                               float* __restrict__ out) {
  const uint64_t e = ((uint64_t)blockIdx.x * 256 + threadIdx.x) * 4;
  f32x4 v = *(const f32x4*)&P[e];
#pragma unroll
  for (int s = 1; s < 8; ++s) v += *(const f32x4*)&P[(uint64_t)s * 2097152 + e];
#pragma unroll
  for (int j = 0; j < 4; ++j) v[j] = fmaxf(v[j], 0.0f);
  if (OUT_MODE == 0) {
    u32x2 w;
    w[0] = (uint32_t)f2bf(v[0]) | ((uint32_t)f2bf(v[1]) << 16);
    w[1] = (uint32_t)f2bf(v[2]) | ((uint32_t)f2bf(v[3]) << 16);
    *(u32x2*)&z1[e] = w;
  } else {
    const int m = (int)(e >> 8);
    const int c = (int)(e & 255);
    *(f32x4*)&out[(((uint64_t)(c >> 6)) * MK + m) * 64 + (c & 63)] = v;
  }
}

extern "C" void kernel_launch(void* const* d_in, const int* in_sizes, int n_in,
                              void* d_out, int out_size, void* d_ws, size_t ws_size,
                              hipStream_t stream) {
  const float* x   = (const float*)d_in[0];
  const float* net = (const float*)d_in[2];
  const float* A   = (const float*)d_in[3];
  float* out = (float*)d_out;

  uint16_t* Ab = (uint16_t*)d_ws;                                        // 128 MiB
  uint16_t* Zt = (uint16_t*)((char*)d_ws + 134217728ull);                // 4 MiB
  uint16_t* z1 = (uint16_t*)((char*)d_ws + 138412032ull);                // 4 MiB
  float*    P  = (float*)   ((char*)d_ws + 142606336ull);                // 64 MiB

  cvtA<<<dim3(2048), dim3(256), 0, stream>>>(A, Ab);
  zw_kernel<0><<<dim3(128, 4), dim3(256), 0, stream>>>(x, (const uint16_t*)nullptr, net, Zt);
  gemm8<<<dim3(256), dim3(512), 0, stream>>>(Ab, Zt, P);
  combine<0><<<dim3(2048), dim3(256), 0, stream>>>(P, z1, (float*)nullptr);
  zw_kernel<1><<<dim3(128, 4), dim3(256), 0, stream>>>((const float*)nullptr, z1, net, Zt);
  gemm8<<<dim3(256), dim3(512), 0, stream>>>(Ab, Zt, P);
  combine<1><<<dim3(2048), dim3(256), 0, stream>>>(P, (uint16_t*)nullptr, out);
}

// Round 4
// 184.072 us; speedup vs baseline: 1.2531x; 1.2531x over previous
//
#include <hip/hip_runtime.h>
#include <stdint.h>

// B=4, N=8192, F=64, L=2:  z = x; 2x: z = relu(A @ z @ W_l)  ==  relu(A @ (z @ W_l))
// Pipeline (5 dispatches):
//   zw0:      Zt[c=b*64+g][n] = sum_f x[b,n,f] W0[f,g]            (bf16, K-major)
//   gemm1:    P[s][m][c] = sum_{k in s} A[m,k] Zt[c][k]           A read as NT f32,
//             cvt->bf16 in-reg, ds_write (swizzled) + store Ab bf16 (cached for gemm2)
//   zw1P:     rows = relu(sum_s P[s])  (fused combine);  Zt = rows @ W1
//   gemm2:    P[s][m][c] = sum_{k in s} Ab[m,k] Zt[c][k]          (global_load_lds)
//   combineF: out = relu(sum_s P[s])  -> f32 [4][8192][64]
// GEMM geometry: BM=256 BN=256(=N) BK=64, splitK=8 (grid 256, s=bid%8 per-XCD K-chunk),
// 8 waves (2x4), wave tile 128x64, double-buffered LDS (128 KiB), single barrier/tile
// (round-2-proven sync), octet-XOR swizzle: stored[r][o] = src[r][o^(r&7)] both paths.
//
// ws: [0,128Mi) Ab | [128Mi,+4Mi) Zt | [136Mi,+64Mi) P

#define MK 8192

typedef float f32x4 __attribute__((ext_vector_type(4)));
typedef uint32_t u32x4 __attribute__((ext_vector_type(4)));
typedef uint32_t u32x2 __attribute__((ext_vector_type(2)));
typedef __bf16 bf16x8 __attribute__((ext_vector_type(8)));

__device__ inline uint16_t f2bf(float f) {
  uint32_t u = __builtin_bit_cast(uint32_t, f);
  u += 0x7fffu + ((u >> 16) & 1u);   // RNE (finite randn inputs)
  return (uint16_t)(u >> 16);
}

#define GLD(src, dstbase)                                                                    \
  __builtin_amdgcn_global_load_lds((const __attribute__((address_space(1))) uint32_t*)(src), \
                                   (__attribute__((address_space(3))) uint32_t*)(dstbase),   \
                                   16, 0, 0)

// ---------------- zw0: Zt = (x @ W0)^T ----------------------------------------------------
__global__ __launch_bounds__(256) void zw0(const float* __restrict__ x,
                                           const float* __restrict__ net,
                                           uint16_t* __restrict__ Zt) {
  __shared__ float Wl[64 * 64];
  __shared__ float rows[64][65];
  const int b = blockIdx.y, n0 = blockIdx.x * 64, tid = threadIdx.x;
  for (int i = tid * 4; i < 4096; i += 1024) {
    f32x4 v = *(const f32x4*)(net + i);
    Wl[i] = v[0]; Wl[i + 1] = v[1]; Wl[i + 2] = v[2]; Wl[i + 3] = v[3];
  }
  const float* src = x + ((uint64_t)b * MK + n0) * 64;
  for (int i = tid * 4; i < 4096; i += 1024) {
    f32x4 v = *(const f32x4*)(src + i);
    int r = i >> 6, f = i & 63;
    rows[r][f] = v[0]; rows[r][f + 1] = v[1]; rows[r][f + 2] = v[2]; rows[r][f + 3] = v[3];
  }
  __syncthreads();
  const int nl = tid & 63, g0 = (tid >> 6) * 16;
  float s[16];
#pragma unroll
  for (int j = 0; j < 16; ++j) s[j] = 0.f;
  for (int f = 0; f < 64; ++f) {
    float rv = rows[nl][f];
#pragma unroll
    for (int j = 0; j < 16; ++j) s[j] = fmaf(rv, Wl[f * 64 + g0 + j], s[j]);
  }
  uint16_t* dst = Zt + (uint64_t)(b * 64 + g0) * MK + n0 + nl;
#pragma unroll
  for (int j = 0; j < 16; ++j) dst[(uint64_t)j * MK] = f2bf(s[j]);
}

// ---------------- gemm1: A nt-f32 -> cvt -> LDS/Ab; P[s] = A @ Zt^T (K-chunk) -------------
__global__ __launch_bounds__(512, 2) void gemm1(const float* __restrict__ Af,
                                                const uint16_t* __restrict__ Bt,
                                                uint16_t* __restrict__ Ab,
                                                float* __restrict__ P) {
  __shared__ __align__(16) uint16_t As[2][16384];   // 256r x 64k bf16, 32 KB/buf
  __shared__ __align__(16) uint16_t Bs[2][16384];
  const int bid = (int)blockIdx.x;
  const int s = bid & 7, bm = bid >> 3;
  const int row0 = bm * 256, k0 = s * 1024;
  const int tid = threadIdx.x, wid = tid >> 6, lane = tid & 63;
  const int wr = wid >> 2, wc = wid & 3;

  // B staging via global_load_lds: 32 chunks (8r x 64k = 1KB), 4/wave; pre-swizzled src.
  const int lsub = lane >> 3;
  const int ksrc = ((lane & 7) ^ lsub) << 3;
  const uint16_t* gB0 = Bt + (uint64_t)(4 * wid * 8 + lsub) * MK + k0 + ksrc;
  const int lBo = 4 * wid * 512;

  // A staging: 64 chunks (4r x 64k f32 = 1KB), 8/wave; lane -> row l>>4, k (l&15)*4.
  const int arow = (8 * wid) * 4 + (lane >> 4);    // tile row for j=0
  const int acol = (lane & 15) * 4;
  const float* gA0 = Af + (uint64_t)(row0 + arow) * MK + k0 + acol;
  const int koct = (lane & 15) >> 1, krem = (lane & 1) * 4;

  f32x4 acc[8][4] = {};
  f32x4 rv[8];

  auto loadA = [&](int kofs) {
#pragma unroll
    for (int j = 0; j < 8; ++j)
      rv[j] = __builtin_nontemporal_load((const f32x4*)(gA0 + (uint64_t)j * 4 * MK + kofs));
  };
  auto stageA = [&](int buf, int kofs) {   // cvt + swizzled ds_write + Ab store
#pragma unroll
    for (int j = 0; j < 8; ++j) {
      const int r = arow + j * 4;
      u32x2 w;
      w[0] = (uint32_t)f2bf(rv[j][0]) | ((uint32_t)f2bf(rv[j][1]) << 16);
      w[1] = (uint32_t)f2bf(rv[j][2]) | ((uint32_t)f2bf(rv[j][3]) << 16);
      *(u32x2*)&As[buf][r * 64 + ((koct ^ (r & 7)) << 3) + krem] = w;
      *(u32x2*)(Ab + (uint64_t)(row0 + r) * MK + k0 + kofs + acol) = w;
    }
  };

  // prologue: tile 0 -> buf 0
  loadA(0);
#pragma unroll
  for (int j = 0; j < 4; ++j) GLD(gB0 + (uint64_t)j * 8 * MK, &Bs[0][lBo + j * 512]);
  stageA(0, 0);
  __syncthreads();

  int buf = 0;
  for (int t = 0; t < 16; ++t) {
    const int nxt = (t + 1) * 64;
    if (t < 15) {
      loadA(nxt);                                   // issue early (hides under MFMA)
#pragma unroll
      for (int j = 0; j < 4; ++j) GLD(gB0 + (uint64_t)j * 8 * MK + nxt, &Bs[buf ^ 1][lBo + j * 512]);
    }
#pragma unroll
    for (int kk = 0; kk < 2; ++kk) {
      const int kb = kk * 4 + (lane >> 4);
      bf16x8 a[8], b[4];
#pragma unroll
      for (int mi = 0; mi < 8; ++mi) {
        const int r = wr * 128 + mi * 16 + (lane & 15);
        a[mi] = *(const bf16x8*)&As[buf][r * 64 + ((kb ^ (r & 7)) << 3)];
      }
#pragma unroll
      for (int n = 0; n < 4; ++n) {
        const int r = wc * 64 + n * 16 + (lane & 15);
        b[n] = *(const bf16x8*)&Bs[buf][r * 64 + ((kb ^ (r & 7)) << 3)];
      }
#pragma unroll
      for (int mi = 0; mi < 8; ++mi)
#pragma unroll
        for (int n = 0; n < 4; ++n)
          acc[mi][n] = __builtin_amdgcn_mfma_f32_16x16x32_bf16(a[mi], b[n], acc[mi][n], 0, 0, 0);
    }
    if (t < 15) stageA(buf ^ 1, nxt);               // write late (loads have landed by now)
    __syncthreads();
    buf ^= 1;
  }

  float* Pp = P + (uint64_t)s * 2097152;
  const int lr = (lane >> 4) * 4, lc = lane & 15;
#pragma unroll
  for (int mi = 0; mi < 8; ++mi)
#pragma unroll
    for (int n = 0; n < 4; ++n) {
      const int gr = row0 + wr * 128 + mi * 16 + lr;
      const int gc = wc * 64 + n * 16 + lc;
#pragma unroll
      for (int j = 0; j < 4; ++j)
        Pp[(uint64_t)(gr + j) * 256 + gc] = acc[mi][n][j];
    }
}

// ---------------- gemm2: pure bf16 (Ab L3-resident), same geometry ------------------------
__global__ __launch_bounds__(512, 2) void gemm2(const uint16_t* __restrict__ Ab,
                                                const uint16_t* __restrict__ Bt,
                                                float* __restrict__ P) {
  __shared__ __align__(16) uint16_t As[2][16384];
  __shared__ __align__(16) uint16_t Bs[2][16384];
  const int bid = (int)blockIdx.x;
  const int s = bid & 7, bm = bid >> 3;
  const int row0 = bm * 256, k0 = s * 1024;
  const int tid = threadIdx.x, wid = tid >> 6, lane = tid & 63;
  const int wr = wid >> 2, wc = wid & 3;

  const int lsub = lane >> 3;
  const int ksrc = ((lane & 7) ^ lsub) << 3;
  const uint16_t* gA0 = Ab + (uint64_t)(row0 + 4 * wid * 8 + lsub) * MK + k0 + ksrc;
  const uint16_t* gB0 = Bt + (uint64_t)(4 * wid * 8 + lsub) * MK + k0 + ksrc;
  const int lo = 4 * wid * 512;

  f32x4 acc[8][4] = {};

#pragma unroll
  for (int j = 0; j < 4; ++j) {
    GLD(gA0 + (uint64_t)j * 8 * MK, &As[0][lo + j * 512]);
    GLD(gB0 + (uint64_t)j * 8 * MK, &Bs[0][lo + j * 512]);
  }
  __syncthreads();

  int buf = 0;
  for (int t = 0; t < 16; ++t) {
    if (t < 15) {
      const int nxt = (t + 1) * 64;
#pragma unroll
      for (int j = 0; j < 4; ++j) {
        GLD(gA0 + (uint64_t)j * 8 * MK + nxt, &As[buf ^ 1][lo + j * 512]);
        GLD(gB0 + (uint64_t)j * 8 * MK + nxt, &Bs[buf ^ 1][lo + j * 512]);
      }
    }
#pragma unroll
    for (int kk = 0; kk < 2; ++kk) {
      const int kb = kk * 4 + (lane >> 4);
      bf16x8 a[8], b[4];
#pragma unroll
      for (int mi = 0; mi < 8; ++mi) {
        const int r = wr * 128 + mi * 16 + (lane & 15);
        a[mi] = *(const bf16x8*)&As[buf][r * 64 + ((kb ^ (r & 7)) << 3)];
      }
#pragma unroll
      for (int n = 0; n < 4; ++n) {
        const int r = wc * 64 + n * 16 + (lane & 15);
        b[n] = *(const bf16x8*)&Bs[buf][r * 64 + ((kb ^ (r & 7)) << 3)];
      }
#pragma unroll
      for (int mi = 0; mi < 8; ++mi)
#pragma unroll
        for (int n = 0; n < 4; ++n)
          acc[mi][n] = __builtin_amdgcn_mfma_f32_16x16x32_bf16(a[mi], b[n], acc[mi][n], 0, 0, 0);
    }
    __syncthreads();
    buf ^= 1;
  }

  float* Pp = P + (uint64_t)s * 2097152;
  const int lr = (lane >> 4) * 4, lc = lane & 15;
#pragma unroll
  for (int mi = 0; mi < 8; ++mi)
#pragma unroll
    for (int n = 0; n < 4; ++n) {
      const int gr = row0 + wr * 128 + mi * 16 + lr;
      const int gc = wc * 64 + n * 16 + lc;
#pragma unroll
      for (int j = 0; j < 4; ++j)
        Pp[(uint64_t)(gr + j) * 256 + gc] = acc[mi][n][j];
    }
}

// ---------------- zw1P: rows = relu(sum_s P[s]); Zt = rows @ W1 (fused combine) -----------
__global__ __launch_bounds__(256) void zw1P(const float* __restrict__ P,
                                            const float* __restrict__ net,
                                            uint16_t* __restrict__ Zt) {
  __shared__ float Wl[64 * 64];
  __shared__ float rows[64][65];
  const int b = blockIdx.y, n0 = blockIdx.x * 64, tid = threadIdx.x;
  const float* Wsrc = net + 4096;
  for (int i = tid * 4; i < 4096; i += 1024) {
    f32x4 v = *(const f32x4*)(Wsrc + i);
    Wl[i] = v[0]; Wl[i + 1] = v[1]; Wl[i + 2] = v[2]; Wl[i + 3] = v[3];
  }
#pragma unroll
  for (int g = 0; g < 4; ++g) {
    const int idx = (tid + g * 256) * 4;
    const int r = idx >> 6, f0 = idx & 63;
    const float* base = P + (uint64_t)(n0 + r) * 256 + b * 64 + f0;
    f32x4 v = *(const f32x4*)base;
#pragma unroll
    for (int s = 1; s < 8; ++s) v += *(const f32x4*)(base + (uint64_t)s * 2097152);
#pragma unroll
    for (int j = 0; j < 4; ++j) rows[r][f0 + j] = fmaxf(v[j], 0.0f);
  }
  __syncthreads();
  const int nl = tid & 63, g0 = (tid >> 6) * 16;
  float s[16];
#pragma unroll
  for (int j = 0; j < 16; ++j) s[j] = 0.f;
  for (int f = 0; f < 64; ++f) {
    float rv = rows[nl][f];
#pragma unroll
    for (int j = 0; j < 16; ++j) s[j] = fmaf(rv, Wl[f * 64 + g0 + j], s[j]);
  }
  uint16_t* dst = Zt + (uint64_t)(b * 64 + g0) * MK + n0 + nl;
#pragma unroll
  for (int j = 0; j < 16; ++j) dst[(uint64_t)j * MK] = f2bf(s[j]);
}

// ---------------- combineF: out = relu(sum_s P[s]) -> f32 [4][8192][64] -------------------
__global__ __launch_bounds__(256) void combineF(const float* __restrict__ P,
                                                float* __restrict__ out) {
  const uint64_t e = ((uint64_t)blockIdx.x * 256 + threadIdx.x) * 4;
  f32x4 v = *(const f32x4*)&P[e];
#pragma unroll
  for (int s = 1; s < 8; ++s) v += *(const f32x4*)&P[(uint64_t)s * 2097152 + e];
#pragma unroll
  for (int j = 0; j < 4; ++j) v[j] = fmaxf(v[j], 0.0f);
  const int m = (int)(e >> 8);
  const int c = (int)(e & 255);
  *(f32x4*)&out[(((uint64_t)(c >> 6)) * MK + m) * 64 + (c & 63)] = v;
}

extern "C" void kernel_launch(void* const* d_in, const int* in_sizes, int n_in,
                              void* d_out, int out_size, void* d_ws, size_t ws_size,
                              hipStream_t stream) {
  const float* x   = (const float*)d_in[0];
  const float* net = (const float*)d_in[2];
  const float* A   = (const float*)d_in[3];
  float* out = (float*)d_out;

  uint16_t* Ab = (uint16_t*)d_ws;                               // 128 MiB
  uint16_t* Zt = (uint16_t*)((char*)d_ws + 134217728ull);       // 4 MiB
  float*    P  = (float*)   ((char*)d_ws + 142606336ull);       // 64 MiB

  zw0<<<dim3(128, 4), dim3(256), 0, stream>>>(x, net, Zt);
  gemm1<<<dim3(256), dim3(512), 0, stream>>>(A, Zt, Ab, P);
  zw1P<<<dim3(128, 4), dim3(256), 0, stream>>>(P, net, Zt);
  gemm2<<<dim3(256), dim3(512), 0, stream>>>(Ab, Zt, P);
  combineF<<<dim3(2048), dim3(256), 0, stream>>>(P, out);
}

// Round 5
// 172.022 us; speedup vs baseline: 1.3409x; 1.0700x over previous
//
#include <hip/hip_runtime.h>
#include <stdint.h>

// B=4, N=8192, F=64, L=2:  z = x; 2x: z = relu(A @ z @ W_l)  ==  relu(A @ (z @ W_l))
// Pipeline (5 dispatches):
//   zw0:      Zt[c=b*64+g][n] = sum_f x[b,n,f] W0[f,g]            (bf16, K-major)
//   gemm1:    P[s][m][c] (bf16) = sum_{k in s} A[m,k] Zt[c][k]    A read NT f32,
//             cvt->bf16 in-reg, swizzled ds_write + store Ab bf16 (cached for gemm2)
//   zw1P:     rows = relu(sum_s P[s])  (fused combine);  Zt = rows @ W1
//   gemm2:    P[s][m][c] (bf16) = sum_{k in s} Ab[m,k] Zt[c][k]   counted-vmcnt pipeline:
//             all 8 GLD of tile t+1 at body start, vmcnt(8) (never 0), raw s_barrier x2,
//             4 reg-phases (B-in-reg, A-quadrant, setprio MFMA clusters).
//   combineF: out = relu(sum_s P[s])  -> f32 [4][8192][64]
// GEMM geometry: BM=256 BN=256(=N) BK=64, splitK=8 (grid 256, s=bid%8 per-XCD K-chunk),
// 8 waves (2x4), wave tile 128x64, LDS 128 KiB dbuf, octet-XOR swizzle both paths.
//
// ws: [0,128Mi) Ab | [128Mi,+4Mi) Zt | [136Mi,+32Mi) P (bf16 [8][8192][256])

#define MK 8192

typedef float f32x4 __attribute__((ext_vector_type(4)));
typedef uint32_t u32x4 __attribute__((ext_vector_type(4)));
typedef uint32_t u32x2 __attribute__((ext_vector_type(2)));
typedef __bf16 bf16x8 __attribute__((ext_vector_type(8)));

__device__ inline uint16_t f2bf(float f) {
  uint32_t u = __builtin_bit_cast(uint32_t, f);
  u += 0x7fffu + ((u >> 16) & 1u);   // RNE (finite randn inputs)
  return (uint16_t)(u >> 16);
}
__device__ inline float bf2f(uint32_t lo16) {
  return __builtin_bit_cast(float, lo16 << 16);
}

#define GLD(src, dstbase)                                                                    \
  __builtin_amdgcn_global_load_lds((const __attribute__((address_space(1))) uint32_t*)(src), \
                                   (__attribute__((address_space(3))) uint32_t*)(dstbase),   \
                                   16, 0, 0)

// ---------------- zw0: Zt = (x @ W0)^T ----------------------------------------------------
__global__ __launch_bounds__(256) void zw0(const float* __restrict__ x,
                                           const float* __restrict__ net,
                                           uint16_t* __restrict__ Zt) {
  __shared__ float Wl[64 * 64];
  __shared__ float rows[64][65];
  const int b = blockIdx.y, n0 = blockIdx.x * 64, tid = threadIdx.x;
  for (int i = tid * 4; i < 4096; i += 1024) {
    f32x4 v = *(const f32x4*)(net + i);
    Wl[i] = v[0]; Wl[i + 1] = v[1]; Wl[i + 2] = v[2]; Wl[i + 3] = v[3];
  }
  const float* src = x + ((uint64_t)b * MK + n0) * 64;
  for (int i = tid * 4; i < 4096; i += 1024) {
    f32x4 v = *(const f32x4*)(src + i);
    int r = i >> 6, f = i & 63;
    rows[r][f] = v[0]; rows[r][f + 1] = v[1]; rows[r][f + 2] = v[2]; rows[r][f + 3] = v[3];
  }
  __syncthreads();
  const int nl = tid & 63, g0 = (tid >> 6) * 16;
  float s[16];
#pragma unroll
  for (int j = 0; j < 16; ++j) s[j] = 0.f;
  for (int f = 0; f < 64; ++f) {
    float rv = rows[nl][f];
#pragma unroll
    for (int j = 0; j < 16; ++j) s[j] = fmaf(rv, Wl[f * 64 + g0 + j], s[j]);
  }
  uint16_t* dst = Zt + (uint64_t)(b * 64 + g0) * MK + n0 + nl;
#pragma unroll
  for (int j = 0; j < 16; ++j) dst[(uint64_t)j * MK] = f2bf(s[j]);
}

// ---------------- gemm1: A nt-f32 -> cvt -> LDS/Ab; P[s](bf16) = A @ Zt^T -----------------
__global__ __launch_bounds__(512, 2) void gemm1(const float* __restrict__ Af,
                                                const uint16_t* __restrict__ Bt,
                                                uint16_t* __restrict__ Ab,
                                                uint16_t* __restrict__ P) {
  __shared__ __align__(16) uint16_t As[2][16384];
  __shared__ __align__(16) uint16_t Bs[2][16384];
  const int bid = (int)blockIdx.x;
  const int s = bid & 7, bm = bid >> 3;
  const int row0 = bm * 256, k0 = s * 1024;
  const int tid = threadIdx.x, wid = tid >> 6, lane = tid & 63;
  const int wr = wid >> 2, wc = wid & 3;

  const int lsub = lane >> 3;
  const int ksrc = ((lane & 7) ^ lsub) << 3;
  const uint16_t* gB0 = Bt + (uint64_t)(4 * wid * 8 + lsub) * MK + k0 + ksrc;
  const int lBo = 4 * wid * 512;

  const int arow = (8 * wid) * 4 + (lane >> 4);
  const int acol = (lane & 15) * 4;
  const float* gA0 = Af + (uint64_t)(row0 + arow) * MK + k0 + acol;
  const int koct = (lane & 15) >> 1, krem = (lane & 1) * 4;

  f32x4 acc[8][4] = {};
  f32x4 rv[8];

  auto loadA = [&](int kofs) {
#pragma unroll
    for (int j = 0; j < 8; ++j)
      rv[j] = __builtin_nontemporal_load((const f32x4*)(gA0 + (uint64_t)j * 4 * MK + kofs));
  };
  auto stageA = [&](int buf, int kofs) {
#pragma unroll
    for (int j = 0; j < 8; ++j) {
      const int r = arow + j * 4;
      u32x2 w;
      w[0] = (uint32_t)f2bf(rv[j][0]) | ((uint32_t)f2bf(rv[j][1]) << 16);
      w[1] = (uint32_t)f2bf(rv[j][2]) | ((uint32_t)f2bf(rv[j][3]) << 16);
      *(u32x2*)&As[buf][r * 64 + ((koct ^ (r & 7)) << 3) + krem] = w;
      *(u32x2*)(Ab + (uint64_t)(row0 + r) * MK + k0 + kofs + acol) = w;
    }
  };

  loadA(0);
#pragma unroll
  for (int j = 0; j < 4; ++j) GLD(gB0 + (uint64_t)j * 8 * MK, &Bs[0][lBo + j * 512]);
  stageA(0, 0);
  __syncthreads();

  int buf = 0;
  for (int t = 0; t < 16; ++t) {
    const int nxt = (t + 1) * 64;
    if (t < 15) {
      loadA(nxt);
#pragma unroll
      for (int j = 0; j < 4; ++j) GLD(gB0 + (uint64_t)j * 8 * MK + nxt, &Bs[buf ^ 1][lBo + j * 512]);
    }
#pragma unroll
    for (int kk = 0; kk < 2; ++kk) {
      const int kb = kk * 4 + (lane >> 4);
      bf16x8 a[8], b[4];
#pragma unroll
      for (int mi = 0; mi < 8; ++mi) {
        const int r = wr * 128 + mi * 16 + (lane & 15);
        a[mi] = *(const bf16x8*)&As[buf][r * 64 + ((kb ^ (r & 7)) << 3)];
      }
#pragma unroll
      for (int n = 0; n < 4; ++n) {
        const int r = wc * 64 + n * 16 + (lane & 15);
        b[n] = *(const bf16x8*)&Bs[buf][r * 64 + ((kb ^ (r & 7)) << 3)];
      }
#pragma unroll
      for (int mi = 0; mi < 8; ++mi)
#pragma unroll
        for (int n = 0; n < 4; ++n)
          acc[mi][n] = __builtin_amdgcn_mfma_f32_16x16x32_bf16(a[mi], b[n], acc[mi][n], 0, 0, 0);
    }
    if (t < 15) stageA(buf ^ 1, nxt);
    __syncthreads();
    buf ^= 1;
  }

  uint16_t* Pp = P + (uint64_t)s * 2097152;
  const int lr = (lane >> 4) * 4, lc = lane & 15;
#pragma unroll
  for (int mi = 0; mi < 8; ++mi)
#pragma unroll
    for (int n = 0; n < 4; ++n) {
      const int gr = row0 + wr * 128 + mi * 16 + lr;
      const int gc = wc * 64 + n * 16 + lc;
#pragma unroll
      for (int j = 0; j < 4; ++j)
        Pp[(uint64_t)(gr + j) * 256 + gc] = f2bf(acc[mi][n][j]);
    }
}

// ---------------- gemm2: counted-vmcnt pipelined bf16 GEMM --------------------------------
__global__ __launch_bounds__(512, 2) void gemm2(const uint16_t* __restrict__ Ab,
                                                const uint16_t* __restrict__ Bt,
                                                uint16_t* __restrict__ P) {
  __shared__ __align__(16) uint16_t As[2][16384];
  __shared__ __align__(16) uint16_t Bs[2][16384];
  const int bid = (int)blockIdx.x;
  const int s = bid & 7, bm = bid >> 3;
  const int row0 = bm * 256, k0 = s * 1024;
  const int tid = threadIdx.x, wid = tid >> 6, lane = tid & 63;
  const int wr = wid >> 2, wc = wid & 3;

  const int lsub = lane >> 3;
  const int ksrc = ((lane & 7) ^ lsub) << 3;
  const uint16_t* gA0 = Ab + (uint64_t)(row0 + 4 * wid * 8 + lsub) * MK + k0 + ksrc;
  const uint16_t* gB0 = Bt + (uint64_t)(4 * wid * 8 + lsub) * MK + k0 + ksrc;
  const int lo = 4 * wid * 512;

  f32x4 acc[8][4] = {};

  // prologue: stage tile 0 -> buf 0 (8 GLD/thread)
#pragma unroll
  for (int j = 0; j < 4; ++j) {
    GLD(gA0 + (uint64_t)j * 8 * MK, &As[0][lo + j * 512]);
    GLD(gB0 + (uint64_t)j * 8 * MK, &Bs[0][lo + j * 512]);
  }

  int buf = 0;
  for (int t = 0; t < 16; ++t) {
    // stage tile t+1 (clamped re-stage on last iter keeps the vmcnt ledger uniform)
    const int tko = ((t + 1) < 16 ? (t + 1) : 15) * 64;
#pragma unroll
    for (int j = 0; j < 4; ++j) {
      GLD(gA0 + (uint64_t)j * 8 * MK + tko, &As[buf ^ 1][lo + j * 512]);
      GLD(gB0 + (uint64_t)j * 8 * MK + tko, &Bs[buf ^ 1][lo + j * 512]);
    }
    // own tile-t 8 loads retired; tile-(t+1)'s 8 stay in flight across the whole tile
    asm volatile("s_waitcnt vmcnt(8)" ::: "memory");
    __builtin_amdgcn_s_barrier();          // join: every wave's tile-t DMA landed
    __builtin_amdgcn_sched_barrier(0);     // pin: no ds_read hoists above the join

    bf16x8 b[4][2];
#pragma unroll
    for (int n = 0; n < 4; ++n)
#pragma unroll
      for (int kk = 0; kk < 2; ++kk) {
        const int r = wc * 64 + n * 16 + (lane & 15);
        const int kb = kk * 4 + (lane >> 4);
        b[n][kk] = *(const bf16x8*)&Bs[buf][r * 64 + ((kb ^ (r & 7)) << 3)];
      }
#pragma unroll
    for (int q = 0; q < 4; ++q) {          // 4 reg-phases: A-quadrant + 16 MFMA
      bf16x8 a[2][2];
#pragma unroll
      for (int i = 0; i < 2; ++i)
#pragma unroll
        for (int kk = 0; kk < 2; ++kk) {
          const int r = wr * 128 + (2 * q + i) * 16 + (lane & 15);
          const int kb = kk * 4 + (lane >> 4);
          a[i][kk] = *(const bf16x8*)&As[buf][r * 64 + ((kb ^ (r & 7)) << 3)];
        }
      __builtin_amdgcn_s_setprio(1);
#pragma unroll
      for (int kk = 0; kk < 2; ++kk)
#pragma unroll
        for (int i = 0; i < 2; ++i)
#pragma unroll
          for (int n = 0; n < 4; ++n)
            acc[2 * q + i][n] =
                __builtin_amdgcn_mfma_f32_16x16x32_bf16(a[i][kk], b[n][kk], acc[2 * q + i][n], 0, 0, 0);
      __builtin_amdgcn_s_setprio(0);
      __builtin_amdgcn_sched_barrier(0);   // keep phases from merging (reg pressure)
    }
    __builtin_amdgcn_s_barrier();          // all reads of buf done -> next GLD may overwrite
    buf ^= 1;
  }

  uint16_t* Pp = P + (uint64_t)s * 2097152;
  const int lr = (lane >> 4) * 4, lc = lane & 15;
#pragma unroll
  for (int mi = 0; mi < 8; ++mi)
#pragma unroll
    for (int n = 0; n < 4; ++n) {
      const int gr = row0 + wr * 128 + mi * 16 + lr;
      const int gc = wc * 64 + n * 16 + lc;
#pragma unroll
      for (int j = 0; j < 4; ++j)
        Pp[(uint64_t)(gr + j) * 256 + gc] = f2bf(acc[mi][n][j]);
    }
}

// ---------------- zw1P: rows = relu(sum_s P[s] (bf16)); Zt = rows @ W1 --------------------
__global__ __launch_bounds__(256) void zw1P(const uint16_t* __restrict__ P,
                                            const float* __restrict__ net,
                                            uint16_t* __restrict__ Zt) {
  __shared__ float Wl[64 * 64];
  __shared__ float rows[64][65];
  const int b = blockIdx.y, n0 = blockIdx.x * 64, tid = threadIdx.x;
  const float* Wsrc = net + 4096;
  for (int i = tid * 4; i < 4096; i += 1024) {
    f32x4 v = *(const f32x4*)(Wsrc + i);
    Wl[i] = v[0]; Wl[i + 1] = v[1]; Wl[i + 2] = v[2]; Wl[i + 3] = v[3];
  }
#pragma unroll
  for (int g = 0; g < 2; ++g) {
    const int idx = (tid + g * 256) * 8;     // 4096 elems = 64 rows x 64 f
    const int r = idx >> 6, f0 = idx & 63;
    const uint16_t* base = P + (uint64_t)(n0 + r) * 256 + b * 64 + f0;
    float acc8[8] = {};
#pragma unroll
    for (int sp = 0; sp < 8; ++sp) {
      u32x4 v = *(const u32x4*)(base + (uint64_t)sp * 2097152);
#pragma unroll
      for (int j = 0; j < 4; ++j) {
        acc8[2 * j]     += bf2f(v[j] & 0xffffu);
        acc8[2 * j + 1] += bf2f(v[j] >> 16);
      }
    }
#pragma unroll
    for (int j = 0; j < 8; ++j) rows[r][f0 + j] = fmaxf(acc8[j], 0.0f);
  }
  __syncthreads();
  const int nl = tid & 63, g0 = (tid >> 6) * 16;
  float s[16];
#pragma unroll
  for (int j = 0; j < 16; ++j) s[j] = 0.f;
  for (int f = 0; f < 64; ++f) {
    float rv = rows[nl][f];
#pragma unroll
    for (int j = 0; j < 16; ++j) s[j] = fmaf(rv, Wl[f * 64 + g0 + j], s[j]);
  }
  uint16_t* dst = Zt + (uint64_t)(b * 64 + g0) * MK + n0 + nl;
#pragma unroll
  for (int j = 0; j < 16; ++j) dst[(uint64_t)j * MK] = f2bf(s[j]);
}

// ---------------- combineF: out = relu(sum_s P[s] (bf16)) -> f32 [4][8192][64] ------------
__global__ __launch_bounds__(256) void combineF(const uint16_t* __restrict__ P,
                                                float* __restrict__ out) {
  const uint64_t e = ((uint64_t)blockIdx.x * 256 + threadIdx.x) * 8;
  float acc8[8] = {};
#pragma unroll
  for (int sp = 0; sp < 8; ++sp) {
    u32x4 v = *(const u32x4*)&P[(uint64_t)sp * 2097152 + e];
#pragma unroll
    for (int j = 0; j < 4; ++j) {
      acc8[2 * j]     += bf2f(v[j] & 0xffffu);
      acc8[2 * j + 1] += bf2f(v[j] >> 16);
    }
  }
  const int m = (int)(e >> 8);
  const int c = (int)(e & 255);
  float* dst = &out[(((uint64_t)(c >> 6)) * MK + m) * 64 + (c & 63)];
  f32x4 w0, w1;
#pragma unroll
  for (int j = 0; j < 4; ++j) { w0[j] = fmaxf(acc8[j], 0.0f); w1[j] = fmaxf(acc8[4 + j], 0.0f); }
  *(f32x4*)dst = w0;
  *(f32x4*)(dst + 4) = w1;
}

extern "C" void kernel_launch(void* const* d_in, const int* in_sizes, int n_in,
                              void* d_out, int out_size, void* d_ws, size_t ws_size,
                              hipStream_t stream) {
  const float* x   = (const float*)d_in[0];
  const float* net = (const float*)d_in[2];
  const float* A   = (const float*)d_in[3];
  float* out = (float*)d_out;

  uint16_t* Ab = (uint16_t*)d_ws;                               // 128 MiB
  uint16_t* Zt = (uint16_t*)((char*)d_ws + 134217728ull);       // 4 MiB
  uint16_t* P  = (uint16_t*)((char*)d_ws + 142606336ull);       // 32 MiB (bf16 [8][8192][256])

  zw0<<<dim3(128, 4), dim3(256), 0, stream>>>(x, net, Zt);
  gemm1<<<dim3(256), dim3(512), 0, stream>>>(A, Zt, Ab, P);
  zw1P<<<dim3(128, 4), dim3(256), 0, stream>>>(P, net, Zt);
  gemm2<<<dim3(256), dim3(512), 0, stream>>>(Ab, Zt, P);
  combineF<<<dim3(1024), dim3(256), 0, stream>>>(P, out);
}